// Round 1
// baseline (1724.430 us; speedup 1.0000x reference)
//
#include <hip/hip_runtime.h>

// Problem: VectorQuantization — N=32768 points, K=8192 codes, D=256 (fp32).
// out[n] = argmin_k ( ||x_n||^2 + ||c_k||^2 - 2 x_n . c_k )  as int32.
//
// Structure:
//   1) norms_kernel : x2[N], c2[K] (one wave per row, float4 + shfl reduce)
//   2) vq_main      : fused GEMM+argmin. 128x128 tile, 8x8 micro-tile/thread,
//                     BK=32 LDS staging (transposed, +4 pad), split-K=4.
//                     split = blockIdx&3 so each XCD (blockIdx%8) streams a
//                     single 2MB code chunk -> fits per-XCD L2.
//   3) vq_combine   : lexicographic (d2, idx) min over the 4 split partials
//                     (matches np.argmin first-occurrence tie rule).
// Workspace: x2(32768f) + c2(8192f) + pd(4*32768f) + pi(4*32768 i32) ~ 1.2 MB.

#define N_PTS 32768
#define K_CB  8192
#define D_DIM 256
#define TM 128
#define TN 128
#define BK 32
#define SPLITK 4
#define KCHUNK (K_CB / SPLITK)   // 2048
#define NTILES (KCHUNK / TN)     // 16
#define LDS_STRIDE (TM + 4)      // 132: pad keeps LDS conflicts <= 2-way (free)

__global__ void __launch_bounds__(256)
norms_kernel(const float* __restrict__ x, const float* __restrict__ vecs,
             float* __restrict__ x2, float* __restrict__ c2) {
    int gwave = (blockIdx.x * 256 + threadIdx.x) >> 6;   // one wave per row
    int lane  = threadIdx.x & 63;
    const float* src;
    float* dst;
    if (gwave < N_PTS) { src = x    + (size_t)gwave * D_DIM;          dst = x2 + gwave; }
    else               { src = vecs + (size_t)(gwave - N_PTS) * D_DIM; dst = c2 + (gwave - N_PTS); }
    float4 v = ((const float4*)src)[lane];               // 64 lanes x 4 = 256
    float s = v.x * v.x + v.y * v.y + v.z * v.z + v.w * v.w;
#pragma unroll
    for (int off = 32; off > 0; off >>= 1) s += __shfl_down(s, off, 64);
    if (lane == 0) *dst = s;
}

__global__ void __launch_bounds__(256)
vq_main(const float* __restrict__ x, const float* __restrict__ vecs,
        const float* __restrict__ x2, const float* __restrict__ c2,
        float* __restrict__ pd, int* __restrict__ pi) {
    __shared__ float xs[BK * LDS_STRIDE];   // [d][point], transposed
    __shared__ float cs[BK * LDS_STRIDE];   // [d][code],  transposed

    const int t     = threadIdx.x;
    const int split = blockIdx.x & (SPLITK - 1);
    const int pbase = (blockIdx.x >> 2) * TM;      // 256 point-blocks
    const int kbase = split * KCHUNK;

    const int lane = t & 63;
    const int wv   = t >> 6;                // 4 waves, 2x2 over the 128x128 tile
    const int wy   = wv >> 1, wx = wv & 1;
    const int ly   = lane >> 3, lx = lane & 7;     // wave as 8x8 lanes
    const int prow = wy * 64 + ly * 8;      // this thread's 8 points (contig)
    const int crow = wx * 64 + lx * 8;      // this thread's 8 codes in tile
    const int txcol = wx * 8 + lx;          // 16 thread-columns per point-row

    // staging: 256 threads x 4 float4 = 4096 floats per tile chunk
    const int srow = t >> 3;                // 0..31
    const int sdg  = t & 7;                 // which float4 of the 32-d chunk

    float x2v[8];
#pragma unroll
    for (int i = 0; i < 8; ++i) x2v[i] = x2[pbase + prow + i];

    float best[8];
    int   bidx[8];
#pragma unroll
    for (int i = 0; i < 8; ++i) { best[i] = 3.4e38f; bidx[i] = 0; }

    for (int kt = 0; kt < NTILES; ++kt) {
        const int ktbase = kbase + kt * TN;

        float acc[8][8];
#pragma unroll
        for (int i = 0; i < 8; ++i)
#pragma unroll
            for (int j = 0; j < 8; ++j) acc[i][j] = 0.0f;

        for (int dc = 0; dc < D_DIM; dc += BK) {
            __syncthreads();   // protect LDS from previous chunk's readers
#pragma unroll
            for (int r = 0; r < 4; ++r) {
                const int row = srow + r * 32;
                const float4 v = *(const float4*)&x[(size_t)(pbase + row) * D_DIM + dc + sdg * 4];
                xs[(sdg * 4 + 0) * LDS_STRIDE + row] = v.x;
                xs[(sdg * 4 + 1) * LDS_STRIDE + row] = v.y;
                xs[(sdg * 4 + 2) * LDS_STRIDE + row] = v.z;
                xs[(sdg * 4 + 3) * LDS_STRIDE + row] = v.w;
                const float4 w = *(const float4*)&vecs[(size_t)(ktbase + row) * D_DIM + dc + sdg * 4];
                cs[(sdg * 4 + 0) * LDS_STRIDE + row] = w.x;
                cs[(sdg * 4 + 1) * LDS_STRIDE + row] = w.y;
                cs[(sdg * 4 + 2) * LDS_STRIDE + row] = w.z;
                cs[(sdg * 4 + 3) * LDS_STRIDE + row] = w.w;
            }
            __syncthreads();
#pragma unroll
            for (int d = 0; d < BK; ++d) {
                const float4* xr = (const float4*)&xs[d * LDS_STRIDE + prow];
                const float4* cr = (const float4*)&cs[d * LDS_STRIDE + crow];
                const float4 a0 = xr[0], a1 = xr[1];
                const float4 b0 = cr[0], b1 = cr[1];
                const float xf[8] = {a0.x, a0.y, a0.z, a0.w, a1.x, a1.y, a1.z, a1.w};
                const float cf[8] = {b0.x, b0.y, b0.z, b0.w, b1.x, b1.y, b1.z, b1.w};
#pragma unroll
                for (int i = 0; i < 8; ++i)
#pragma unroll
                    for (int j = 0; j < 8; ++j)
                        acc[i][j] = fmaf(xf[i], cf[j], acc[i][j]);
            }
        }

        // merge this code tile into the running per-point argmin
        const float4* c2p = (const float4*)&c2[ktbase + crow];
        const float4 q0 = c2p[0], q1 = c2p[1];
        const float c2v[8] = {q0.x, q0.y, q0.z, q0.w, q1.x, q1.y, q1.z, q1.w};
#pragma unroll
        for (int i = 0; i < 8; ++i) {
#pragma unroll
            for (int j = 0; j < 8; ++j) {
                const float d2 = (x2v[i] + c2v[j]) - 2.0f * acc[i][j];
                const int kg = ktbase + crow + j;
                if (d2 < best[i]) { best[i] = d2; bidx[i] = kg; }  // strict <: keeps lowest k (ascending scan)
            }
        }
    }

    // block-level reduction across the 16 thread-columns per point
    __syncthreads();
    float* rd = xs;          // 128 points x 16 cols = 2048 floats (fits in xs)
    int*   ri = (int*)cs;
#pragma unroll
    for (int i = 0; i < 8; ++i) {
        const int p = prow + i;
        rd[p * 16 + txcol] = best[i];
        ri[p * 16 + txcol] = bidx[i];
    }
    __syncthreads();
    if (t < TM) {
        float bb = rd[t * 16];
        int   bi = ri[t * 16];
#pragma unroll
        for (int c = 1; c < 16; ++c) {
            const float v  = rd[t * 16 + c];
            const int   vi = ri[t * 16 + c];
            if (v < bb || (v == bb && vi < bi)) { bb = v; bi = vi; }
        }
        pd[split * N_PTS + pbase + t] = bb;
        pi[split * N_PTS + pbase + t] = bi;
    }
}

__global__ void __launch_bounds__(256)
vq_combine(const float* __restrict__ pd, const int* __restrict__ pi,
           int* __restrict__ out) {
    const int p = blockIdx.x * 256 + threadIdx.x;
    float bb = pd[p];
    int   bi = pi[p];
#pragma unroll
    for (int s = 1; s < SPLITK; ++s) {
        const float v  = pd[s * N_PTS + p];
        const int   vi = pi[s * N_PTS + p];
        if (v < bb || (v == bb && vi < bi)) { bb = v; bi = vi; }
    }
    out[p] = bi;
}

extern "C" void kernel_launch(void* const* d_in, const int* in_sizes, int n_in,
                              void* d_out, int out_size, void* d_ws, size_t ws_size,
                              hipStream_t stream) {
    const float* x    = (const float*)d_in[0];
    const float* vecs = (const float*)d_in[1];
    float* wsf = (float*)d_ws;
    float* x2 = wsf;                                   // 32768
    float* c2 = wsf + N_PTS;                           // 8192
    float* pd = wsf + N_PTS + K_CB;                    // SPLITK*32768
    int*   pi = (int*)(wsf + N_PTS + K_CB + SPLITK * N_PTS);
    int*   out = (int*)d_out;

    hipLaunchKernelGGL(norms_kernel, dim3((N_PTS + K_CB) / 4), dim3(256), 0, stream,
                       x, vecs, x2, c2);
    hipLaunchKernelGGL(vq_main, dim3((N_PTS / TM) * SPLITK), dim3(256), 0, stream,
                       x, vecs, x2, c2, pd, pi);
    hipLaunchKernelGGL(vq_combine, dim3(N_PTS / 256), dim3(256), 0, stream,
                       pd, pi, out);
}

// Round 3
// 667.821 us; speedup vs baseline: 2.5822x; 2.5822x over previous
//
#include <hip/hip_runtime.h>

// VectorQuantization — N=32768 points, K=8192 codes, D=256 fp32 -> int32 argmin.
// Round 3 = Round 2 with the compile fix (cvt3 returns a struct; no refs into
// ext_vector elements). Split-f16 MFMA:
//   x.c ~= xh*ch + (xh*2^-11)*(cl*2^11) + (xl*2^11)*(ch*2^-11)
// -> 3 MFMA passes (mfma_f32_16x16x32_f16), one fp32 accumulator, no denorm
// hazard on residual operands. argmin_k(c2[k] - 2*x.c_k) (x2 row-const dropped).
//
// vq_main: 128x128 tile, 4 waves x (4x4) 16x16 tiles, BK=32 chunks, LDS stride
// 36 halves, SPLITK=4 (split=blk&3 -> each XCD streams one 2MB code chunk).
// Strict-< ascending merge == np.argmin first-min tie rule; lex (val,idx) min
// in all cross-lane/cross-split reductions.

#define N_PTS 32768
#define K_CB  8192
#define D_DIM 256
#define TM 128
#define TN 128
#define BK 32
#define SPLITK 4
#define KCHUNK (K_CB / SPLITK)   // 2048
#define NTILES (KCHUNK / TN)     // 16
#define LS (BK + 4)              // 36 halves: 8B-aligned rows, ~2-way banks

typedef _Float16 half4v __attribute__((ext_vector_type(4)));
typedef _Float16 half8v __attribute__((ext_vector_type(8)));
typedef float    f32x4  __attribute__((ext_vector_type(4)));

__device__ inline half8v load8(const _Float16* p) {
    half4v a = *(const half4v*)p;
    half4v b = *(const half4v*)(p + 4);
    return __builtin_shufflevector(a, b, 0, 1, 2, 3, 4, 5, 6, 7);
}

struct Trip { _Float16 h, s2, l2; };

// fp32 -> (head, head*2^-11, resid*2^11) f16 triple
__device__ inline Trip cvt3(float v) {
    Trip t;
    _Float16 hh = (_Float16)v;
    float hf = (float)hh;
    t.h  = hh;
    t.s2 = (_Float16)(hf * 4.8828125e-4f);   // * 2^-11 (exact scale)
    t.l2 = (_Float16)((v - hf) * 2048.0f);   // * 2^11  (exact scale)
    return t;
}

__global__ void __launch_bounds__(256)
cnorms_kernel(const float* __restrict__ vecs, float* __restrict__ c2) {
    int gwave = (blockIdx.x * 256 + threadIdx.x) >> 6;   // one wave per code row
    int lane  = threadIdx.x & 63;
    const float* src = vecs + (size_t)gwave * D_DIM;
    float4 v = ((const float4*)src)[lane];
    float s = v.x * v.x + v.y * v.y + v.z * v.z + v.w * v.w;
#pragma unroll
    for (int off = 32; off > 0; off >>= 1) s += __shfl_down(s, off, 64);
    if (lane == 0) c2[gwave] = s;
}

__global__ void __launch_bounds__(256, 2)
vq_main(const float* __restrict__ x, const float* __restrict__ vecs,
        const float* __restrict__ c2, float* __restrict__ pd, int* __restrict__ pi) {
    __shared__ _Float16 lds[6 * TM * LS];   // 6 arrays x 128 x 36 halves = 54KB
    _Float16* xh  = lds;
    _Float16* xs2 = lds + 1 * TM * LS;
    _Float16* xl2 = lds + 2 * TM * LS;
    _Float16* ch  = lds + 3 * TM * LS;
    _Float16* cl2 = lds + 4 * TM * LS;
    _Float16* cs2 = lds + 5 * TM * LS;

    const int t     = threadIdx.x;
    const int split = blockIdx.x & (SPLITK - 1);
    const int pbase = (blockIdx.x >> 2) * TM;
    const int kbase = split * KCHUNK;

    const int lane = t & 63;
    const int wv   = t >> 6;
    const int wy   = wv >> 1, wx = wv & 1;   // wave quadrant of 128x128
    const int fr   = lane & 15;              // row/col within 16x16 tile
    const int g    = lane >> 4;              // k-group 0..3
    const int kb   = g * 8;                  // frag k base (halves)

    const int srow = t >> 3;                 // staging: 32 rows per pass
    const int sc4  = (t & 7) * 4;            // which 4 cols of the 32-chunk

    float best[16];
    int   bidx[16];
#pragma unroll
    for (int i = 0; i < 16; ++i) { best[i] = 3.4e38f; bidx[i] = 0; }

    for (int kt = 0; kt < NTILES; ++kt) {
        const int ktbase = kbase + kt * TN;

        f32x4 acc[4][4];
#pragma unroll
        for (int i = 0; i < 4; ++i)
#pragma unroll
            for (int j = 0; j < 4; ++j) {
                f32x4 z = {0.f, 0.f, 0.f, 0.f};
                acc[i][j] = z;
            }

        for (int dk = 0; dk < D_DIM; dk += BK) {
            __syncthreads();   // protect LDS from previous chunk's readers
#pragma unroll
            for (int p = 0; p < 4; ++p) {
                const int row = srow + p * 32;
                // x side
                const float4 v = *(const float4*)&x[(size_t)(pbase + row) * D_DIM + dk + sc4];
                const Trip t0 = cvt3(v.x), t1 = cvt3(v.y), t2 = cvt3(v.z), t3 = cvt3(v.w);
                half4v h  = {t0.h,  t1.h,  t2.h,  t3.h};
                half4v s2 = {t0.s2, t1.s2, t2.s2, t3.s2};
                half4v l2 = {t0.l2, t1.l2, t2.l2, t3.l2};
                *(half4v*)&xh [row * LS + sc4] = h;
                *(half4v*)&xs2[row * LS + sc4] = s2;
                *(half4v*)&xl2[row * LS + sc4] = l2;
                // c side (pairing: ch<->xh, cl2=resid*2^11<->xs2, cs2=head*2^-11<->xl2)
                const float4 w = *(const float4*)&vecs[(size_t)(ktbase + row) * D_DIM + dk + sc4];
                const Trip u0 = cvt3(w.x), u1 = cvt3(w.y), u2 = cvt3(w.z), u3 = cvt3(w.w);
                half4v hc = {u0.h,  u1.h,  u2.h,  u3.h};
                half4v sc = {u0.s2, u1.s2, u2.s2, u3.s2};
                half4v lc = {u0.l2, u1.l2, u2.l2, u3.l2};
                *(half4v*)&ch [row * LS + sc4] = hc;
                *(half4v*)&cs2[row * LS + sc4] = sc;
                *(half4v*)&cl2[row * LS + sc4] = lc;
            }
            __syncthreads();

            half8v a1[4], a2[4], a3[4], b1[4], b2[4], b3[4];
#pragma unroll
            for (int i = 0; i < 4; ++i) {
                const int aoff = (wy * 64 + i * 16 + fr) * LS + kb;
                a1[i] = load8(&xh [aoff]);
                a2[i] = load8(&xs2[aoff]);
                a3[i] = load8(&xl2[aoff]);
                const int boff = (wx * 64 + i * 16 + fr) * LS + kb;
                b1[i] = load8(&ch [boff]);
                b2[i] = load8(&cl2[boff]);
                b3[i] = load8(&cs2[boff]);
            }
#pragma unroll
            for (int i = 0; i < 4; ++i)
#pragma unroll
                for (int j = 0; j < 4; ++j) {
                    acc[i][j] = __builtin_amdgcn_mfma_f32_16x16x32_f16(a1[i], b1[j], acc[i][j], 0, 0, 0);
                    acc[i][j] = __builtin_amdgcn_mfma_f32_16x16x32_f16(a2[i], b2[j], acc[i][j], 0, 0, 0);
                    acc[i][j] = __builtin_amdgcn_mfma_f32_16x16x32_f16(a3[i], b3[j], acc[i][j], 0, 0, 0);
                }
        }

        // merge this 128-code tile into running per-row argmin.
        // j ascending + strict < == first-min tie rule within the tile.
#pragma unroll
        for (int j = 0; j < 4; ++j) {
            const int cg = ktbase + wx * 64 + j * 16 + fr;
            const float c2v = c2[cg];
#pragma unroll
            for (int i = 0; i < 4; ++i)
#pragma unroll
                for (int r = 0; r < 4; ++r) {
                    const float v = fmaf(-2.0f, acc[i][j][r], c2v);
                    const int s = i * 4 + r;
                    if (v < best[s]) { best[s] = v; bidx[s] = cg; }
                }
        }
    }

    // final reduction: butterfly across the 16 lanes (cols) holding each row,
    // then across the 2 wave-column-halves via LDS.
    __syncthreads();
    float* rd = (float*)lds;          // 128 x 2 floats
    int*   ri = (int*)lds + 256;      // 128 x 2 ints
#pragma unroll
    for (int i = 0; i < 4; ++i)
#pragma unroll
        for (int r = 0; r < 4; ++r) {
            float bv = best[i * 4 + r];
            int   bi = bidx[i * 4 + r];
#pragma unroll
            for (int off = 1; off < 16; off <<= 1) {
                const float ov = __shfl_xor(bv, off, 64);
                const int   oi = __shfl_xor(bi, off, 64);
                if (ov < bv || (ov == bv && oi < bi)) { bv = ov; bi = oi; }
            }
            if (fr == 0) {
                const int rowl = wy * 64 + i * 16 + g * 4 + r;
                rd[rowl * 2 + wx] = bv;
                ri[rowl * 2 + wx] = bi;
            }
        }
    __syncthreads();
    if (t < TM) {
        float b0 = rd[t * 2];
        int   i0 = ri[t * 2];
        const float b1 = rd[t * 2 + 1];
        const int   i1 = ri[t * 2 + 1];
        if (b1 < b0 || (b1 == b0 && i1 < i0)) { b0 = b1; i0 = i1; }
        pd[split * N_PTS + pbase + t] = b0;
        pi[split * N_PTS + pbase + t] = i0;
    }
}

__global__ void __launch_bounds__(256)
vq_combine(const float* __restrict__ pd, const int* __restrict__ pi,
           int* __restrict__ out) {
    const int p = blockIdx.x * 256 + threadIdx.x;
    float bb = pd[p];
    int   bi = pi[p];
#pragma unroll
    for (int s = 1; s < SPLITK; ++s) {
        const float v  = pd[s * N_PTS + p];
        const int   vi = pi[s * N_PTS + p];
        if (v < bb || (v == bb && vi < bi)) { bb = v; bi = vi; }
    }
    out[p] = bi;
}

extern "C" void kernel_launch(void* const* d_in, const int* in_sizes, int n_in,
                              void* d_out, int out_size, void* d_ws, size_t ws_size,
                              hipStream_t stream) {
    const float* x    = (const float*)d_in[0];
    const float* vecs = (const float*)d_in[1];
    float* wsf = (float*)d_ws;
    float* c2 = wsf;                                   // 8192
    float* pd = wsf + K_CB;                            // SPLITK*32768
    int*   pi = (int*)(wsf + K_CB + SPLITK * N_PTS);
    int*   out = (int*)d_out;

    hipLaunchKernelGGL(cnorms_kernel, dim3(K_CB / 4), dim3(256), 0, stream,
                       vecs, c2);
    hipLaunchKernelGGL(vq_main, dim3((N_PTS / TM) * SPLITK), dim3(256), 0, stream,
                       x, vecs, c2, pd, pi);
    hipLaunchKernelGGL(vq_combine, dim3(N_PTS / 256), dim3(256), 0, stream,
                       pd, pi, out);
}

// Round 4
// 464.380 us; speedup vs baseline: 3.7134x; 1.4381x over previous
//
#include <hip/hip_runtime.h>
#include <stdint.h>
#include <stddef.h>

// VectorQuantization — N=32768, K=8192, D=256 fp32 -> int32 argmin.
// Round 4: precompute f16 split pairs (h, l*2^11) for x and codes to global ws
// (once — round 3 re-converted x 16x inside the loop), then MFMA main kernel
// stages them with global_load_lds width=16 (no VALU, no VGPR round-trip).
// Scale-compensated operands derived in-register: a2=a1*2^-11, b3=b1*2^-11:
//   x.c = xh*ch + (xh*2^-11)*(cl*2^11) + (xl*2^11)*(ch*2^-11)
// LDS layout is DMA lane-order with XOR-of-row k-slot swizzle baked into the
// *source* addresses -> ds_read_b128 fragment loads are exactly 8 words/bank
// (conflict-free). BK=64, single 64KB buffer, 2 blocks/CU. SPLITK=4: split =
// blk&3 with XCD = blk%8 -> each XCD's L2 holds one 2MB code chunk.
// Fallback to the (passing) round-3 kernel if ws_size < 43MB.

#define N_PTS 32768
#define K_CB  8192
#define D_DIM 256
#define TM 128
#define TN 128
#define SPLITK 4
#define KCHUNK (K_CB / SPLITK)   // 2048
#define NTILES (KCHUNK / TN)     // 16

// fast-path ws layout (byte offsets; all 16B-aligned)
#define WS_XH   0
#define WS_XL   (WS_XH + N_PTS * D_DIM * 2)
#define WS_CH   (WS_XL + N_PTS * D_DIM * 2)
#define WS_CL   (WS_CH + K_CB * D_DIM * 2)
#define WS_C2   (WS_CL + K_CB * D_DIM * 2)
#define WS_PD   (WS_C2 + K_CB * 4)
#define WS_PI   (WS_PD + SPLITK * N_PTS * 4)
#define WS_END  (WS_PI + SPLITK * N_PTS * 4)   // 43,024,384 B

typedef _Float16 half4v __attribute__((ext_vector_type(4)));
typedef _Float16 half8v __attribute__((ext_vector_type(8)));
typedef float    f32x4  __attribute__((ext_vector_type(4)));

__device__ __forceinline__ void gld16(const void* g, void* l) {
    __builtin_amdgcn_global_load_lds(
        (const __attribute__((address_space(1))) void*)g,
        (__attribute__((address_space(3))) void*)l, 16, 0, 0);
}

// ---------------- preprocessing ----------------

__global__ void __launch_bounds__(256)
split_kernel(const float* __restrict__ src, _Float16* __restrict__ h_out,
             _Float16* __restrict__ l_out) {
    const int i = blockIdx.x * 256 + threadIdx.x;   // one float4 per thread
    const float4 v = ((const float4*)src)[i];
    half4v h = {(_Float16)v.x, (_Float16)v.y, (_Float16)v.z, (_Float16)v.w};
    half4v l = {(_Float16)((v.x - (float)h[0]) * 2048.0f),
                (_Float16)((v.y - (float)h[1]) * 2048.0f),
                (_Float16)((v.z - (float)h[2]) * 2048.0f),
                (_Float16)((v.w - (float)h[3]) * 2048.0f)};
    *(half4v*)(h_out + (size_t)i * 4) = h;
    *(half4v*)(l_out + (size_t)i * 4) = l;
}

__global__ void __launch_bounds__(256)
cnorms_kernel(const float* __restrict__ vecs, float* __restrict__ c2) {
    int gwave = (blockIdx.x * 256 + threadIdx.x) >> 6;   // one wave per code row
    int lane  = threadIdx.x & 63;
    const float* src = vecs + (size_t)gwave * D_DIM;
    float4 v = ((const float4*)src)[lane];
    float s = v.x * v.x + v.y * v.y + v.z * v.z + v.w * v.w;
#pragma unroll
    for (int off = 32; off > 0; off >>= 1) s += __shfl_down(s, off, 64);
    if (lane == 0) c2[gwave] = s;
}

// ---------------- fast main kernel ----------------

__global__ void __launch_bounds__(256, 2)
vq_main_fast(const _Float16* __restrict__ xh_g, const _Float16* __restrict__ xl_g,
             const _Float16* __restrict__ ch_g, const _Float16* __restrict__ cl_g,
             const float* __restrict__ c2, float* __restrict__ pd, int* __restrict__ pi) {
    // regions: xh [0,16K), xl [16K,32K), ch [32K,48K), cl [48K,64K)
    __shared__ __align__(16) char lds[65536];

    const int t    = threadIdx.x;
    const int lane = t & 63;
    const int wv   = t >> 6;
    const int wy   = wv >> 1, wx = wv & 1;   // wave quadrant of 128x128
    const int fr   = lane & 15;              // row/col within 16x16 tile
    const int g    = lane >> 4;              // k-group 0..3

    const int split = blockIdx.x & (SPLITK - 1);
    const int pbase = (blockIdx.x >> 2) * TM;
    const int kbase = split * KCHUNK;

    // staging: per-lane source offset inside an 8-row block. lane i reads the
    // 16B k-slot k16 = (i%8)^(i/8) of row i/8 -> 8-lane groups cover one
    // contiguous 128B row chunk (perfect coalescing), and the LDS image gets
    // slot s of row r = k-group s^(r&7)  (the XOR swizzle).
    const int rowoff = (lane >> 3) * (D_DIM * 2) + (((lane & 7) ^ (lane >> 3)) << 4);
    const char* xh_w = (const char*)xh_g + (size_t)(pbase + wv * 32) * (D_DIM * 2) + rowoff;
    const char* xl_w = (const char*)xl_g + (size_t)(pbase + wv * 32) * (D_DIM * 2) + rowoff;
    char* ldsA_h = lds +         (wv * 32) * 128;   // wave-uniform DMA bases
    char* ldsA_l = lds + 16384 + (wv * 32) * 128;
    char* ldsB_h = lds + 32768 + (wv * 32) * 128;
    char* ldsB_l = lds + 49152 + (wv * 32) * 128;

    // fragment LDS byte offsets (constant across kt/dkc): row*128 + swizzled slot
    int aoff[4][2], boff[4][2];
#pragma unroll
    for (int i = 0; i < 4; ++i)
#pragma unroll
        for (int ks = 0; ks < 2; ++ks) {
            aoff[i][ks] = (wy * 64 + i * 16 + fr) * 128 + (((ks * 4 + g) ^ (fr & 7)) << 4);
            boff[i][ks] = 32768 + (wx * 64 + i * 16 + fr) * 128 + (((ks * 4 + g) ^ (fr & 7)) << 4);
        }

    float best[16];
    int   bidx[16];
#pragma unroll
    for (int i = 0; i < 16; ++i) { best[i] = 3.4e38f; bidx[i] = 0; }

    for (int kt = 0; kt < NTILES; ++kt) {
        const int ktbase = kbase + kt * TN;
        const char* ch_w = (const char*)ch_g + (size_t)(ktbase + wv * 32) * (D_DIM * 2) + rowoff;
        const char* cl_w = (const char*)cl_g + (size_t)(ktbase + wv * 32) * (D_DIM * 2) + rowoff;

        f32x4 acc[4][4];
#pragma unroll
        for (int i = 0; i < 4; ++i)
#pragma unroll
            for (int j = 0; j < 4; ++j) {
                f32x4 z = {0.f, 0.f, 0.f, 0.f};
                acc[i][j] = z;
            }

#pragma unroll 1
        for (int dkc = 0; dkc < 4; ++dkc) {      // 64-halves K chunks
            const int gofs = dkc * 128;          // byte offset into each row
            __syncthreads();                      // readers of prev chunk done
#pragma unroll
            for (int q = 0; q < 4; ++q) {        // 8 rows per inst, 32 rows/wave
                gld16(xh_w + q * 4096 + gofs, ldsA_h + q * 1024);
                gld16(xl_w + q * 4096 + gofs, ldsA_l + q * 1024);
                gld16(ch_w + q * 4096 + gofs, ldsB_h + q * 1024);
                gld16(cl_w + q * 4096 + gofs, ldsB_l + q * 1024);
            }
            __syncthreads();                      // barrier drains vmcnt (m97)
#pragma unroll
            for (int ks = 0; ks < 2; ++ks) {
                half8v a1[4], a2[4], a3[4];
#pragma unroll
                for (int i = 0; i < 4; ++i) {
                    const char* p = lds + aoff[i][ks];
                    a1[i] = *(const half8v*)p;              // xh
                    a3[i] = *(const half8v*)(p + 16384);    // xl*2^11
                    a2[i] = a1[i] * (_Float16)4.8828125e-4f; // xh*2^-11
                }
#pragma unroll
                for (int j = 0; j < 4; ++j) {
                    const char* p = lds + boff[j][ks];
                    half8v b1 = *(const half8v*)p;              // ch
                    half8v b2 = *(const half8v*)(p + 16384);    // cl*2^11
                    half8v b3 = b1 * (_Float16)4.8828125e-4f;   // ch*2^-11
#pragma unroll
                    for (int i = 0; i < 4; ++i) {
                        acc[i][j] = __builtin_amdgcn_mfma_f32_16x16x32_f16(a1[i], b1, acc[i][j], 0, 0, 0);
                        acc[i][j] = __builtin_amdgcn_mfma_f32_16x16x32_f16(a2[i], b2, acc[i][j], 0, 0, 0);
                        acc[i][j] = __builtin_amdgcn_mfma_f32_16x16x32_f16(a3[i], b3, acc[i][j], 0, 0, 0);
                    }
                }
            }
        }

        // merge tile into running argmin; ascending j + strict < == np first-min
#pragma unroll
        for (int j = 0; j < 4; ++j) {
            const int cg = ktbase + wx * 64 + j * 16 + fr;
            const float c2v = c2[cg];
#pragma unroll
            for (int i = 0; i < 4; ++i)
#pragma unroll
                for (int r = 0; r < 4; ++r) {
                    const float v = fmaf(-2.0f, acc[i][j][r], c2v);
                    const int s = i * 4 + r;
                    if (v < best[s]) { best[s] = v; bidx[s] = cg; }
                }
        }
    }

    // reduce across the 16 lanes holding each point row, then the 2 wave-cols
    __syncthreads();
    float* rd = (float*)lds;          // 128 x 2 floats
    int*   ri = (int*)lds + 256;      // 128 x 2 ints
#pragma unroll
    for (int i = 0; i < 4; ++i)
#pragma unroll
        for (int r = 0; r < 4; ++r) {
            float bv = best[i * 4 + r];
            int   bi = bidx[i * 4 + r];
#pragma unroll
            for (int off = 1; off < 16; off <<= 1) {
                const float ov = __shfl_xor(bv, off, 64);
                const int   oi = __shfl_xor(bi, off, 64);
                if (ov < bv || (ov == bv && oi < bi)) { bv = ov; bi = oi; }
            }
            if (fr == 0) {
                const int rowl = wy * 64 + i * 16 + g * 4 + r;
                rd[rowl * 2 + wx] = bv;
                ri[rowl * 2 + wx] = bi;
            }
        }
    __syncthreads();
    if (t < TM) {
        float b0 = rd[t * 2];
        int   i0 = ri[t * 2];
        const float b1 = rd[t * 2 + 1];
        const int   i1 = ri[t * 2 + 1];
        if (b1 < b0 || (b1 == b0 && i1 < i0)) { b0 = b1; i0 = i1; }
        pd[split * N_PTS + pbase + t] = b0;
        pi[split * N_PTS + pbase + t] = i0;
    }
}

// ---------------- fallback (round-3, passing) ----------------

#define BK 32
#define LS (BK + 4)

__device__ inline half8v load8(const _Float16* p) {
    half4v a = *(const half4v*)p;
    half4v b = *(const half4v*)(p + 4);
    return __builtin_shufflevector(a, b, 0, 1, 2, 3, 4, 5, 6, 7);
}

struct Trip { _Float16 h, s2, l2; };

__device__ inline Trip cvt3(float v) {
    Trip t;
    _Float16 hh = (_Float16)v;
    float hf = (float)hh;
    t.h  = hh;
    t.s2 = (_Float16)(hf * 4.8828125e-4f);
    t.l2 = (_Float16)((v - hf) * 2048.0f);
    return t;
}

__global__ void __launch_bounds__(256, 2)
vq_main_v3(const float* __restrict__ x, const float* __restrict__ vecs,
           const float* __restrict__ c2, float* __restrict__ pd, int* __restrict__ pi) {
    __shared__ _Float16 lds[6 * TM * LS];
    _Float16* xh  = lds;
    _Float16* xs2 = lds + 1 * TM * LS;
    _Float16* xl2 = lds + 2 * TM * LS;
    _Float16* ch  = lds + 3 * TM * LS;
    _Float16* cl2 = lds + 4 * TM * LS;
    _Float16* cs2 = lds + 5 * TM * LS;

    const int t     = threadIdx.x;
    const int split = blockIdx.x & (SPLITK - 1);
    const int pbase = (blockIdx.x >> 2) * TM;
    const int kbase = split * KCHUNK;

    const int lane = t & 63;
    const int wv   = t >> 6;
    const int wy   = wv >> 1, wx = wv & 1;
    const int fr   = lane & 15;
    const int g    = lane >> 4;
    const int kb   = g * 8;

    const int srow = t >> 3;
    const int sc4  = (t & 7) * 4;

    float best[16];
    int   bidx[16];
#pragma unroll
    for (int i = 0; i < 16; ++i) { best[i] = 3.4e38f; bidx[i] = 0; }

    for (int kt = 0; kt < NTILES; ++kt) {
        const int ktbase = kbase + kt * TN;
        f32x4 acc[4][4];
#pragma unroll
        for (int i = 0; i < 4; ++i)
#pragma unroll
            for (int j = 0; j < 4; ++j) {
                f32x4 z = {0.f, 0.f, 0.f, 0.f};
                acc[i][j] = z;
            }
        for (int dk = 0; dk < D_DIM; dk += BK) {
            __syncthreads();
#pragma unroll
            for (int p = 0; p < 4; ++p) {
                const int row = srow + p * 32;
                const float4 v = *(const float4*)&x[(size_t)(pbase + row) * D_DIM + dk + sc4];
                const Trip t0 = cvt3(v.x), t1 = cvt3(v.y), t2 = cvt3(v.z), t3 = cvt3(v.w);
                half4v h  = {t0.h,  t1.h,  t2.h,  t3.h};
                half4v s2 = {t0.s2, t1.s2, t2.s2, t3.s2};
                half4v l2 = {t0.l2, t1.l2, t2.l2, t3.l2};
                *(half4v*)&xh [row * LS + sc4] = h;
                *(half4v*)&xs2[row * LS + sc4] = s2;
                *(half4v*)&xl2[row * LS + sc4] = l2;
                const float4 w = *(const float4*)&vecs[(size_t)(ktbase + row) * D_DIM + dk + sc4];
                const Trip u0 = cvt3(w.x), u1 = cvt3(w.y), u2 = cvt3(w.z), u3 = cvt3(w.w);
                half4v hc = {u0.h,  u1.h,  u2.h,  u3.h};
                half4v sc = {u0.s2, u1.s2, u2.s2, u3.s2};
                half4v lc = {u0.l2, u1.l2, u2.l2, u3.l2};
                *(half4v*)&ch [row * LS + sc4] = hc;
                *(half4v*)&cs2[row * LS + sc4] = sc;
                *(half4v*)&cl2[row * LS + sc4] = lc;
            }
            __syncthreads();
            half8v a1[4], a2[4], a3[4], b1[4], b2[4], b3[4];
#pragma unroll
            for (int i = 0; i < 4; ++i) {
                const int aoff = (wy * 64 + i * 16 + fr) * LS + kb;
                a1[i] = load8(&xh [aoff]);
                a2[i] = load8(&xs2[aoff]);
                a3[i] = load8(&xl2[aoff]);
                const int boff2 = (wx * 64 + i * 16 + fr) * LS + kb;
                b1[i] = load8(&ch [boff2]);
                b2[i] = load8(&cl2[boff2]);
                b3[i] = load8(&cs2[boff2]);
            }
#pragma unroll
            for (int i = 0; i < 4; ++i)
#pragma unroll
                for (int j = 0; j < 4; ++j) {
                    acc[i][j] = __builtin_amdgcn_mfma_f32_16x16x32_f16(a1[i], b1[j], acc[i][j], 0, 0, 0);
                    acc[i][j] = __builtin_amdgcn_mfma_f32_16x16x32_f16(a2[i], b2[j], acc[i][j], 0, 0, 0);
                    acc[i][j] = __builtin_amdgcn_mfma_f32_16x16x32_f16(a3[i], b3[j], acc[i][j], 0, 0, 0);
                }
        }
#pragma unroll
        for (int j = 0; j < 4; ++j) {
            const int cg = ktbase + wx * 64 + j * 16 + fr;
            const float c2v = c2[cg];
#pragma unroll
            for (int i = 0; i < 4; ++i)
#pragma unroll
                for (int r = 0; r < 4; ++r) {
                    const float v = fmaf(-2.0f, acc[i][j][r], c2v);
                    const int s = i * 4 + r;
                    if (v < best[s]) { best[s] = v; bidx[s] = cg; }
                }
        }
    }
    __syncthreads();
    float* rd = (float*)lds;
    int*   ri = (int*)lds + 256;
#pragma unroll
    for (int i = 0; i < 4; ++i)
#pragma unroll
        for (int r = 0; r < 4; ++r) {
            float bv = best[i * 4 + r];
            int   bi = bidx[i * 4 + r];
#pragma unroll
            for (int off = 1; off < 16; off <<= 1) {
                const float ov = __shfl_xor(bv, off, 64);
                const int   oi = __shfl_xor(bi, off, 64);
                if (ov < bv || (ov == bv && oi < bi)) { bv = ov; bi = oi; }
            }
            if (fr == 0) {
                const int rowl = wy * 64 + i * 16 + g * 4 + r;
                rd[rowl * 2 + wx] = bv;
                ri[rowl * 2 + wx] = bi;
            }
        }
    __syncthreads();
    if (t < TM) {
        float b0 = rd[t * 2];
        int   i0 = ri[t * 2];
        const float b1 = rd[t * 2 + 1];
        const int   i1 = ri[t * 2 + 1];
        if (b1 < b0 || (b1 == b0 && i1 < i0)) { b0 = b1; i0 = i1; }
        pd[split * N_PTS + pbase + t] = b0;
        pi[split * N_PTS + pbase + t] = i0;
    }
}

// ---------------- combine ----------------

__global__ void __launch_bounds__(256)
vq_combine(const float* __restrict__ pd, const int* __restrict__ pi,
           int* __restrict__ out) {
    const int p = blockIdx.x * 256 + threadIdx.x;
    float bb = pd[p];
    int   bi = pi[p];
#pragma unroll
    for (int s = 1; s < SPLITK; ++s) {
        const float v  = pd[s * N_PTS + p];
        const int   vi = pi[s * N_PTS + p];
        if (v < bb || (v == bb && vi < bi)) { bb = v; bi = vi; }
    }
    out[p] = bi;
}

extern "C" void kernel_launch(void* const* d_in, const int* in_sizes, int n_in,
                              void* d_out, int out_size, void* d_ws, size_t ws_size,
                              hipStream_t stream) {
    const float* x    = (const float*)d_in[0];
    const float* vecs = (const float*)d_in[1];
    int* out = (int*)d_out;
    char* ws = (char*)d_ws;

    if (ws_size >= (size_t)WS_END) {
        _Float16* xh = (_Float16*)(ws + WS_XH);
        _Float16* xl = (_Float16*)(ws + WS_XL);
        _Float16* ch = (_Float16*)(ws + WS_CH);
        _Float16* cl = (_Float16*)(ws + WS_CL);
        float* c2 = (float*)(ws + WS_C2);
        float* pd = (float*)(ws + WS_PD);
        int*   pi = (int*)(ws + WS_PI);

        hipLaunchKernelGGL(split_kernel, dim3(N_PTS * D_DIM / 4 / 256), dim3(256), 0, stream,
                           x, xh, xl);
        hipLaunchKernelGGL(split_kernel, dim3(K_CB * D_DIM / 4 / 256), dim3(256), 0, stream,
                           vecs, ch, cl);
        hipLaunchKernelGGL(cnorms_kernel, dim3(K_CB / 4), dim3(256), 0, stream,
                           vecs, c2);
        hipLaunchKernelGGL(vq_main_fast, dim3((N_PTS / TM) * SPLITK), dim3(256), 0, stream,
                           xh, xl, ch, cl, c2, pd, pi);
        hipLaunchKernelGGL(vq_combine, dim3(N_PTS / 256), dim3(256), 0, stream,
                           pd, pi, out);
    } else {
        float* c2 = (float*)ws;
        float* pd = (float*)ws + K_CB;
        int*   pi = (int*)((float*)ws + K_CB + SPLITK * N_PTS);
        hipLaunchKernelGGL(cnorms_kernel, dim3(K_CB / 4), dim3(256), 0, stream,
                           vecs, c2);
        hipLaunchKernelGGL(vq_main_v3, dim3((N_PTS / TM) * SPLITK), dim3(256), 0, stream,
                           x, vecs, c2, pd, pi);
        hipLaunchKernelGGL(vq_combine, dim3(N_PTS / 256), dim3(256), 0, stream,
                           pd, pi, out);
    }
}